// Round 7
// baseline (878.093 us; speedup 1.0000x reference)
//
#include <hip/hip_runtime.h>

#define NB 8
#define N_PER 4096
#define N_SAMPLE 1024
#define KNN 64
#define CIN 64
#define HD 128
#define R2F 0.04f
#define LIST_CAP 384
#define STR 136  // h1 bf16 LDS row stride (shorts); 136*2=272B, 16B-aligned

typedef __attribute__((ext_vector_type(8))) short bf16x8;
typedef __attribute__((ext_vector_type(4))) float f32x4;
typedef __attribute__((ext_vector_type(2))) float f32x2;

__device__ __forceinline__ unsigned short f2bf(float f) {
    const unsigned u = __float_as_uint(f);
    return (unsigned short)((u + 0x7fff + ((u >> 16) & 1)) >> 16);  // RNE
}

// ---- DPP wave64 64-bit max-reduce (pure VALU; lane 63 ends with the max) ---
template <int CTRL>
__device__ __forceinline__ unsigned long long dpp_shift_u64(unsigned long long k) {
    const unsigned lo = (unsigned)k;
    const unsigned hi = (unsigned)(k >> 32);
    const unsigned olo =
        (unsigned)__builtin_amdgcn_update_dpp(0, (int)lo, CTRL, 0xf, 0xf, false);
    const unsigned ohi =
        (unsigned)__builtin_amdgcn_update_dpp(0, (int)hi, CTRL, 0xf, 0xf, false);
    return ((unsigned long long)ohi << 32) | olo;
}
__device__ __forceinline__ unsigned long long wave_max_u64(unsigned long long k) {
    unsigned long long o;
    o = dpp_shift_u64<0x111>(k); k = o > k ? o : k;  // row_shr:1
    o = dpp_shift_u64<0x112>(k); k = o > k ? o : k;  // row_shr:2
    o = dpp_shift_u64<0x114>(k); k = o > k ? o : k;  // row_shr:4
    o = dpp_shift_u64<0x118>(k); k = o > k ? o : k;  // row_shr:8
    o = dpp_shift_u64<0x142>(k); k = o > k ? o : k;  // row_bcast:15
    o = dpp_shift_u64<0x143>(k); k = o > k ? o : k;  // row_bcast:31
    return k;                                        // lane 63 holds wave max
}

// ---- FPS (blocks 0..7) + g precompute + W2T bf16 transpose -----------------
// g = x@W1[:64] + pos@W1[64:67] + b1  (per-point part of layer 1)
// W2T[n*128+k] = bf16(W2[k*128+n])  (B-operand-friendly layout)
#define GBLOCKS ((NB * N_PER) / 2)
__global__ __launch_bounds__(256) void fps_g_kernel(const float* __restrict__ pos,
                                                    const float* __restrict__ x,
                                                    const float* __restrict__ W1,
                                                    const float* __restrict__ b1,
                                                    const float* __restrict__ W2,
                                                    float* __restrict__ g,
                                                    short* __restrict__ w2t,
                                                    int* __restrict__ idx_out,
                                                    float* __restrict__ pos_out,
                                                    float* __restrict__ batch_out) {
    __shared__ float pxyz[N_PER * 3];  // interleaved x,y,z
    __shared__ __align__(16) unsigned long long pkey[2][4];
    __shared__ int lhist[N_SAMPLE];
    const int t = threadIdx.x;

    if (blockIdx.x >= NB + GBLOCKS) {
        // ---------------- W2T part: 8 blocks, 8 elems/thread ----------------
        const int base = (int)(blockIdx.x - (NB + GBLOCKS)) * 2048 + t * 8;
#pragma unroll
        for (int i = 0; i < 8; ++i) {
            const int idx = base + i;  // = n*128 + k
            const int n = idx >> 7, k = idx & 127;
            w2t[idx] = (short)f2bf(W2[k * HD + n]);
        }
        return;
    }

    if (blockIdx.x >= NB) {
        // ---------------- g part: 2 points per block ----------------
        const int n0 = (int)(blockIdx.x - NB) * 2;
        if (t < 2 * CIN) pxyz[t] = x[(size_t)n0 * CIN + t];
        if (t < 6) pxyz[512 + t] = pos[(size_t)n0 * 3 + t];
        __syncthreads();
        const int lp = t >> 7;
        const int h = t & 127;
        float acc = b1[h];
        const float* xv = pxyz + lp * CIN;
#pragma unroll 8
        for (int c = 0; c < CIN; ++c) acc += xv[c] * W1[c * HD + h];
        const float* pv = pxyz + 512 + lp * 3;
#pragma unroll
        for (int d = 0; d < 3; ++d) acc += pv[d] * W1[(CIN + d) * HD + h];
        g[(size_t)(n0 + lp) * HD + h] = acc;
        return;
    }

    // ---------------- FPS part: one block per cloud ----------------
    {
#pragma clang fp contract(off)
        const int b = blockIdx.x;
        const float* posb = pos + (size_t)b * N_PER * 3;
        for (int i = t; i < N_PER * 3; i += 256) pxyz[i] = posb[i];
        if (t == 0) lhist[0] = 0;
        __syncthreads();

        // registers hold this thread's 16 points as 8 packed pairs:
        // pair k -> global idx (t + (2k)*256) in .x, (t + (2k+1)*256) in .y
        f32x2 rx[8], ry[8], rz[8], mind[8];
#pragma unroll
        for (int k = 0; k < 8; ++k) {
            const int p0 = t + ((2 * k) << 8);
            const int p1 = t + ((2 * k + 1) << 8);
            rx[k] = (f32x2){pxyz[p0 * 3 + 0], pxyz[p1 * 3 + 0]};
            ry[k] = (f32x2){pxyz[p0 * 3 + 1], pxyz[p1 * 3 + 1]};
            rz[k] = (f32x2){pxyz[p0 * 3 + 2], pxyz[p1 * 3 + 2]};
            mind[k] = (f32x2){1e10f, 1e10f};
        }
        float lx = pxyz[0], ly = pxyz[1], lz = pxyz[2];

        for (int s = 1; s < N_SAMPLE; ++s) {
            const f32x2 lx2 = {lx, lx}, ly2 = {ly, ly}, lz2 = {lz, lz};
            // independent per-pair updates; v_pk_* packed f32; contract(off)
            // keeps exact left-to-right f32 RNE: ((dx*dx)+(dy*dy))+(dz*dz)
#pragma unroll
            for (int k = 0; k < 8; ++k) {
                const f32x2 dx = rx[k] - lx2;
                const f32x2 dy = ry[k] - ly2;
                const f32x2 dz = rz[k] - lz2;
                const f32x2 d = ((dx * dx) + (dy * dy)) + (dz * dz);
                mind[k] = __builtin_elementwise_min(mind[k], d);
            }
            // log-depth tree max (no serial 16-deep cmp chain)
            const f32x2 m01 = __builtin_elementwise_max(mind[0], mind[1]);
            const f32x2 m23 = __builtin_elementwise_max(mind[2], mind[3]);
            const f32x2 m45 = __builtin_elementwise_max(mind[4], mind[5]);
            const f32x2 m67 = __builtin_elementwise_max(mind[6], mind[7]);
            const f32x2 ma = __builtin_elementwise_max(m01, m23);
            const f32x2 mb = __builtin_elementwise_max(m45, m67);
            const f32x2 mt = __builtin_elementwise_max(ma, mb);
            const float bv = fmaxf(mt.x, mt.y);
            // recover smallest global index with mind == bv (exact tie-break):
            // scan high->low so the smallest-index match wins
            int bi = 0;
#pragma unroll
            for (int k = 7; k >= 0; --k) {
                if (mind[k].y == bv) bi = t + ((2 * k + 1) << 8);
                if (mind[k].x == bv) bi = t + ((2 * k) << 8);
            }
            // dists >= 0 so (f32 dist, min idx) order == u64 order of (bits, ~idx)
            unsigned long long key =
                ((unsigned long long)__float_as_uint(bv) << 32) | (unsigned)(~bi);
            key = wave_max_u64(key);

            const int par = s & 1;
            if ((t & 63) == 63) pkey[par][t >> 6] = key;
            __syncthreads();
            const ulonglong2* pk2 = (const ulonglong2*)(&pkey[par][0]);
            const ulonglong2 A = pk2[0], Bq = pk2[1];
            unsigned long long f0 = A.x > A.y ? A.x : A.y;
            const unsigned long long f1 = Bq.x > Bq.y ? Bq.x : Bq.y;
            f0 = f0 > f1 ? f0 : f1;
            const int last = (int)(~(unsigned)f0);
            lx = pxyz[last * 3 + 0];  // broadcast read (same addr all lanes)
            ly = pxyz[last * 3 + 1];
            lz = pxyz[last * 3 + 2];
            if (t == (s & 255)) lhist[s] = last;
            // parity ping-pong on pkey avoids a trailing barrier
        }
        __syncthreads();

        for (int i = t; i < N_SAMPLE; i += 256) {
            const int li = lhist[i];
            idx_out[b * N_SAMPLE + i] = b * N_PER + li;
            pos_out[(size_t)(b * N_SAMPLE + i) * 3 + 0] = pxyz[li * 3 + 0];
            pos_out[(size_t)(b * N_SAMPLE + i) * 3 + 1] = pxyz[li * 3 + 1];
            pos_out[(size_t)(b * N_SAMPLE + i) * 3 + 2] = pxyz[li * 3 + 2];
            batch_out[b * N_SAMPLE + i] = (float)b;
        }
    }
}

// ---- main: ball-query select + bf16 h1 + MFMA layer-2 + masked max ---------
__global__ __launch_bounds__(256) void main_kernel(const float* __restrict__ pos,
                                                   const float* __restrict__ W1,
                                                   const short* __restrict__ W2T,
                                                   const float* __restrict__ b2,
                                                   const float* __restrict__ g,
                                                   const int* __restrict__ idx_in,
                                                   float* __restrict__ x_out) {
    __shared__ short h1b[KNN * STR];  // bf16 [64][STR]
    __shared__ unsigned long long keys[LIST_CAP];
    __shared__ int sel[KNN];
    __shared__ float pcW[HD];
    __shared__ float cp[3];
    __shared__ int cnt;
    __shared__ float stripmax[4][HD];

    const int t = threadIdx.x;
    const int s = blockIdx.x;
    const int b = s >> 10;
    const int gci = idx_in[s];
    if (t < 3) cp[t] = pos[(size_t)gci * 3 + t];
    if (t == 0) cnt = 0;
    __syncthreads();

    if (t < HD) {
        pcW[t] = cp[0] * W1[CIN * HD + t] + cp[1] * W1[(CIN + 1) * HD + t] +
                 cp[2] * W1[(CIN + 2) * HD + t];
    }

    const float cx = cp[0], cy = cp[1], cz = cp[2];
    const size_t base = (size_t)b * N_PER;
    const int lane = t & 63;
#pragma unroll
    for (int k = 0; k < 16; ++k) {
        const int p = t + (k << 8);
        const float* pp = pos + (base + p) * 3;
        const float dx = pp[0] - cx;
        const float dy = pp[1] - cy;
        const float dz = pp[2] - cz;
        const float d2 = __fadd_rn(__fadd_rn(__fmul_rn(dx, dx), __fmul_rn(dy, dy)),
                                   __fmul_rn(dz, dz));
        const bool hit = (d2 <= R2F);
        const unsigned long long m = __ballot(hit);
        if (m) {
            const int leader = __ffsll((unsigned long long)m) - 1;
            int wb = 0;
            if (lane == leader) wb = atomicAdd(&cnt, __popcll(m));
            wb = __shfl(wb, leader);
            if (hit) {
                const int slot = wb + __popcll(m & ((1ull << lane) - 1));
                if (slot < LIST_CAP)
                    keys[slot] =
                        ((unsigned long long)__float_as_uint(d2) << 32) | (unsigned)p;
            }
        }
    }
    __syncthreads();
    const int C = min(cnt, LIST_CAP);
    const int M = min(C, KNN);

    // exact top-K by rank of (d2, idx) key (matches lax.top_k tie semantics)
    for (int e = t; e < C; e += 256) {
        const unsigned long long ke = keys[e];
        int rank = 0;
        for (int q = 0; q < C; ++q) rank += (keys[q] < ke) ? 1 : 0;
        if (rank < KNN) sel[rank] = (int)(ke & 0xFFFFFFFFull);
    }
    __syncthreads();

    // h1[m][h] = relu(g[j_m][h] - pcW[h]) -> bf16 into LDS (zeros for m >= M)
    for (int lin = t; lin < KNN * (HD / 2); lin += 256) {
        const int m = lin >> 6;
        const int hp = lin & 63;  // handles h = 2hp, 2hp+1
        float v0 = 0.0f, v1 = 0.0f;
        if (m < M) {
            const float2 gv = *(const float2*)(g + (base + sel[m]) * HD + 2 * hp);
            v0 = fmaxf(gv.x - pcW[2 * hp], 0.0f);
            v1 = fmaxf(gv.y - pcW[2 * hp + 1], 0.0f);
        }
        const unsigned pk = (unsigned)f2bf(v0) | ((unsigned)f2bf(v1) << 16);
        *(unsigned*)(&h1b[m * STR + 2 * hp]) = pk;
    }
    __syncthreads();

    // layer 2 via MFMA 16x16x32 bf16. Wave w owns m-strip [16w,16w+16).
    // A[m=lane&15][k=quad*8+j] (m120-verified), C/D col=lane&15,row=quad*4+reg (m89).
    const int w = t >> 6;
    const int row = lane & 15;
    const int kg = lane >> 4;  // quad

    bf16x8 afr[4];
#pragma unroll
    for (int kc = 0; kc < 4; ++kc)
        afr[kc] = *(const bf16x8*)(&h1b[(w * 16 + row) * STR + kc * 32 + kg * 8]);

#pragma unroll
    for (int nt = 0; nt < 8; ++nt) {
        f32x4 acc = {0.0f, 0.0f, 0.0f, 0.0f};
#pragma unroll
        for (int kc = 0; kc < 4; ++kc) {
            const bf16x8 bfr =
                *(const bf16x8*)(W2T + (nt * 16 + row) * HD + kc * 32 + kg * 8);
            acc = __builtin_amdgcn_mfma_f32_16x16x32_bf16(afr[kc], bfr, acc, 0, 0, 0);
        }
        const float bb = b2[nt * 16 + row];
        float mxv = -1e9f;
#pragma unroll
        for (int r = 0; r < 4; ++r) {
            const int m = w * 16 + kg * 4 + r;
            const float v = fmaxf(acc[r] + bb, 0.0f);
            if (m < M) mxv = fmaxf(mxv, v);
        }
        mxv = fmaxf(mxv, __shfl_xor(mxv, 16));
        mxv = fmaxf(mxv, __shfl_xor(mxv, 32));
        if (lane < 16) stripmax[w][nt * 16 + lane] = mxv;
    }
    __syncthreads();
    if (t < HD) {
        const float v = fmaxf(fmaxf(stripmax[0][t], stripmax[1][t]),
                              fmaxf(stripmax[2][t], stripmax[3][t]));
        x_out[(size_t)s * HD + t] = v;
    }
}

extern "C" void kernel_launch(void* const* d_in, const int* in_sizes, int n_in,
                              void* d_out, int out_size, void* d_ws, size_t ws_size,
                              hipStream_t stream) {
    const float* x   = (const float*)d_in[0];
    const float* pos = (const float*)d_in[1];
    const float* W1  = (const float*)d_in[2];
    const float* b1  = (const float*)d_in[3];
    const float* W2  = (const float*)d_in[4];
    const float* b2  = (const float*)d_in[5];

    float* out = (float*)d_out;
    float* x_out     = out;                                  // [8192,128]
    float* pos_out   = out + (size_t)NB * N_SAMPLE * HD;     // [8192,3]
    float* batch_out = pos_out + (size_t)NB * N_SAMPLE * 3;  // [8192]

    int*   idx_ws = (int*)d_ws;                              // [0,32K): 8192 ints
    short* w2t    = (short*)((char*)d_ws + 32768);           // [32K,64K): bf16 W2T
    float* g      = (float*)((char*)d_ws + 65536);           // [64K,+16M): [32768,128] f32

    fps_g_kernel<<<NB + GBLOCKS + 8, 256, 0, stream>>>(pos, x, W1, b1, W2, g, w2t,
                                                       idx_ws, pos_out, batch_out);
    main_kernel<<<NB * N_SAMPLE, 256, 0, stream>>>(pos, W1, w2t, b2, g, idx_ws, x_out);
}